// Round 9
// baseline (54.398 us; speedup 1.0000x reference)
//
#include <hip/hip_runtime.h>
#include <hip/hip_bf16.h>

#define HW        1659      // 21*79
#define GLYPH_DIM 1536

typedef _Float16 half8  __attribute__((ext_vector_type(8)));
typedef _Float16 half2v __attribute__((ext_vector_type(2)));
typedef float    f32x4  __attribute__((ext_vector_type(4)));

__device__ __forceinline__ unsigned int pk(float a, float b) {
    return __builtin_bit_cast(unsigned int, __builtin_amdgcn_cvt_pkrtz(a, b));
}

__device__ __forceinline__ half8 h8u(unsigned int a, unsigned int b,
                                     unsigned int c, unsigned int d) {
    uint4 u = make_uint4(a, b, c, d);
    return __builtin_bit_cast(half8, u);
}

// packed-f16 tanh on 2 lanes: Pade(5,4) x(945+105y+y^2)/(945+420y+15y^2),
// input clamp +-4, output clamp +-1. Max abs err < 2e-3. v_pk_* codegen.
__device__ __forceinline__ unsigned int tanh_pk(unsigned int w) {
    const half2v hP4  = {(_Float16)4.0f,  (_Float16)4.0f};
    const half2v hM4  = {(_Float16)-4.0f, (_Float16)-4.0f};
    const half2v h105 = {(_Float16)105.0f, (_Float16)105.0f};
    const half2v h945 = {(_Float16)945.0f, (_Float16)945.0f};
    const half2v h15  = {(_Float16)15.0f,  (_Float16)15.0f};
    const half2v h420 = {(_Float16)420.0f, (_Float16)420.0f};
    const half2v hP1  = {(_Float16)1.0f,  (_Float16)1.0f};
    const half2v hM1  = {(_Float16)-1.0f, (_Float16)-1.0f};
    half2v x = __builtin_bit_cast(half2v, w);
    x = __builtin_elementwise_max(__builtin_elementwise_min(x, hP4), hM4);
    half2v y   = x * x;
    half2v num = x * (y * (y + h105) + h945);
    half2v den = y * (y * h15 + h420) + h945;
    half2v r   = num / den;
    r = __builtin_elementwise_max(__builtin_elementwise_min(r, hP1), hM1);
    return __builtin_bit_cast(unsigned int, r);
}

__device__ __forceinline__ void unpack4(uint4 p, f32x4& c0, f32x4& c1) {
    half2v a = __builtin_bit_cast(half2v, p.x);
    half2v b = __builtin_bit_cast(half2v, p.y);
    half2v c = __builtin_bit_cast(half2v, p.z);
    half2v d = __builtin_bit_cast(half2v, p.w);
    c0[0] = (float)a[0]; c0[1] = (float)a[1];
    c0[2] = (float)b[0]; c0[3] = (float)b[1];
    c1[0] = (float)c[0]; c1[1] = (float)c[1];
    c1[2] = (float)d[0]; c1[3] = (float)d[1];
}

// ---------------- K1: histogram -> sorted unique ids + lens ----------------
__global__ __launch_bounds__(256, 8) void k1_histo(
    const int* __restrict__ gchar, const int* __restrict__ gcol,
    unsigned short* __restrict__ ids_bt,    // [B][64]
    unsigned short* __restrict__ ids_tb16,  // [B/16][64 t][16 b-in-group]
    int* __restrict__ lens_g)
{
    __shared__ unsigned int   mask[4][48];
    __shared__ unsigned short ids_s[4][64];

    const int tid = threadIdx.x;
    const int b0  = blockIdx.x * 4;

    if (tid < 192) ((unsigned int*)mask)[tid] = 0u;
    __syncthreads();

    const int4* cp = (const int4*)(gchar + (long)b0 * HW);
    const int4* kp = (const int4*)(gcol  + (long)b0 * HW);
    const int n4 = HW;
    int idx = tid;
    bool valid = idx < n4;
    int4 c = {}, k = {};
    if (valid) { c = cp[idx]; k = kp[idx]; }
    while (valid) {
        int  idx1 = idx + 256;
        bool v1   = idx1 < n4;
        int4 c1 = {}, k1 = {};
        if (v1) { c1 = cp[idx1]; k1 = kp[idx1]; }
        {
            int gg  = idx * 4;
            int bl0 = gg / HW;
            int rem = gg - bl0 * HW;
            int bl1 = bl0 + ((rem + 1) >= HW);
            int bl2 = bl0 + ((rem + 2) >= HW);
            int bl3 = bl0 + ((rem + 3) >= HW);
            int id0 = c.x * 16 + k.x;
            int id1 = c.y * 16 + k.y;
            int id2 = c.z * 16 + k.z;
            int id3 = c.w * 16 + k.w;
            atomicOr(&mask[bl0][id0 >> 5], 1u << (id0 & 31));
            atomicOr(&mask[bl1][id1 >> 5], 1u << (id1 & 31));
            atomicOr(&mask[bl2][id2 >> 5], 1u << (id2 & 31));
            atomicOr(&mask[bl3][id3 >> 5], 1u << (id3 & 31));
        }
        idx = idx1; valid = v1; c = c1; k = k1;
    }
    __syncthreads();

    if (tid < 128) {
        const int bl  = tid >> 5;
        const int l32 = tid & 31;
        unsigned long long m = 0ull;
        if (l32 < 24)
            m = ((unsigned long long)mask[bl][2 * l32 + 1] << 32) |
                (unsigned long long)mask[bl][2 * l32];
        int cnt  = __popcll(m);
        int incl = cnt;
        #pragma unroll
        for (int d = 1; d < 32; d <<= 1) {
            int nb = __shfl_up(incl, d, 32);
            if (l32 >= d) incl += nb;
        }
        int excl  = incl - cnt;
        int total = __shfl(incl, 31, 32);
        if (l32 == 0) lens_g[b0 + bl] = min(total, 64);
        ids_s[bl][l32]      = GLYPH_DIM;
        ids_s[bl][l32 + 32] = GLYPH_DIM;
        unsigned long long mm = m;
        int r = excl;
        while (mm != 0ull && r < 64) {
            int bit = __builtin_ctzll(mm);
            ids_s[bl][r] = (unsigned short)(l32 * 64 + bit);
            ++r;
            mm &= (mm - 1ull);
        }
    }
    __syncthreads();

    if (tid < 128)
        ((unsigned int*)(ids_bt + (long)b0 * 64))[tid] = ((unsigned int*)ids_s)[tid];
    {
        const int bl = tid >> 6, t = tid & 63;
        const int b  = b0 + bl;
        ids_tb16[((long)(b >> 4) * 64 + t) * 16 + (b & 15)] = ids_s[bl][t];
    }
}

// ---------------- K23: blocks [0,nrnn): RNN; [nrnn,...): emb/bag ----------
// tau(g,j) = {4g..4g+3, 16+4g..19+4g} consistently on A and B; C/D layout
// (col=lane&15=batch, row=(lane>>4)*4+reg) feeds next step's B-fragment.
__global__ __launch_bounds__(256, 2) void k23_main(
    const float* __restrict__ ctab, const float* __restrict__ ktab,
    const float* __restrict__ Wih, const float* __restrict__ Whh,
    const float* __restrict__ bih, const float* __restrict__ bhh,
    const unsigned short* __restrict__ ids_bt,
    const unsigned short* __restrict__ ids_tb16,
    const int* __restrict__ lens_g,
    float* __restrict__ out_h, float* __restrict__ out_emb,
    float* __restrict__ out_bag, int nrnn)
{
    __shared__ __align__(16) uint4 P_lds[64 * 64];   // 64 KB
    __shared__ float tabs[1620];                     // emb path only

    const int tid = threadIdx.x;

    if ((int)blockIdx.x < nrnn) {
        // ---------------- RNN path: one 16-batch group ----------------
        const int bg = blockIdx.x;
        const int l  = tid & 63, w = tid >> 6;
        const int n  = l & 15,  g = l >> 4;

        half8 wihA0, wihA1;
        f32x4 bias0, bias1;
        #pragma unroll
        for (int j = 0; j < 8; ++j) {
            int kk = (j < 4) ? (4 * g + j) : (12 + 4 * g + j);
            wihA0[j] = (_Float16)((kk < 20) ? Wih[n * 20 + kk] : 0.0f);
            wihA1[j] = (_Float16)((kk < 20) ? Wih[(n + 16) * 20 + kk] : 0.0f);
        }
        #pragma unroll
        for (int i = 0; i < 4; ++i) {
            bias0[i] = bih[4 * g + i] + bhh[4 * g + i];
            bias1[i] = bih[16 + 4 * g + i] + bhh[16 + 4 * g + i];
        }

        // prologue: 4 waves compute P[t] = Wih@x_t + bias for 16 t's each
        const unsigned short* idp = ids_tb16 + (long)bg * 1024;
        #pragma unroll 4
        for (int tt = 0; tt < 16; ++tt) {
            int t  = w * 16 + tt;
            int id = idp[t * 16 + n];
            int ch = id >> 4;
            int co = (id >= GLYPH_DIM) ? 16 : (id & 15);
            f32x4 q1 = *(const f32x4*)(ctab + ch * 16 + 4 * g);
            f32x4 q2 = {0.0f, 0.0f, 0.0f, 0.0f};
            if (g == 0) q2 = *(const f32x4*)(ktab + co * 4);
            half8 xB = h8u(pk(q1[0], q1[1]), pk(q1[2], q1[3]),
                           pk(q2[0], q2[1]), pk(q2[2], q2[3]));
            f32x4 P0 = __builtin_amdgcn_mfma_f32_16x16x32_f16(wihA0, xB, bias0, 0, 0, 0);
            f32x4 P1 = __builtin_amdgcn_mfma_f32_16x16x32_f16(wihA1, xB, bias1, 0, 0, 0);
            P_lds[t * 64 + l] = make_uint4(pk(P0[0], P0[1]), pk(P0[2], P0[3]),
                                           pk(P1[0], P1[1]), pk(P1[2], P1[3]));
        }
        __syncthreads();

        if (w == 0) {
            half8 whhA0, whhA1;
            #pragma unroll
            for (int j = 0; j < 8; ++j) {
                int kk = (j < 4) ? (4 * g + j) : (12 + 4 * g + j);
                whhA0[j] = (_Float16)Whh[n * 32 + kk];
                whhA1[j] = (_Float16)Whh[(n + 16) * 32 + kk];
            }
            const int len = lens_g[bg * 16 + n];
            unsigned int hw0 = 0u, hw1 = 0u, hw2 = 0u, hw3 = 0u;
            uint4 pc = P_lds[l];
            f32x4 cc0, cc1;
            unpack4(pc, cc0, cc1);
            for (int t = 0; t < 64; ++t) {
                uint4 pn = P_lds[((t < 63) ? t + 1 : 63) * 64 + l];
                half8 hB = h8u(hw0, hw1, hw2, hw3);
                f32x4 a0 = __builtin_amdgcn_mfma_f32_16x16x32_f16(whhA0, hB, cc0, 0, 0, 0);
                f32x4 a1 = __builtin_amdgcn_mfma_f32_16x16x32_f16(whhA1, hB, cc1, 0, 0, 0);
                unpack4(pn, cc0, cc1);                 // off-chain, for next step
                unsigned int t0 = tanh_pk(pk(a0[0], a0[1]));
                unsigned int t1 = tanh_pk(pk(a0[2], a0[3]));
                unsigned int t2 = tanh_pk(pk(a1[0], a1[1]));
                unsigned int t3 = tanh_pk(pk(a1[2], a1[3]));
                bool upd = (t < len);
                hw0 = upd ? t0 : hw0;
                hw1 = upd ? t1 : hw1;
                hw2 = upd ? t2 : hw2;
                hw3 = upd ? t3 : hw3;
            }
            float* op = out_h + (long)(bg * 16 + n) * 32;
            half2v u0 = __builtin_bit_cast(half2v, hw0);
            half2v u1 = __builtin_bit_cast(half2v, hw1);
            half2v u2 = __builtin_bit_cast(half2v, hw2);
            half2v u3 = __builtin_bit_cast(half2v, hw3);
            op[4 * g + 0]      = (float)u0[0];
            op[4 * g + 1]      = (float)u0[1];
            op[4 * g + 2]      = (float)u1[0];
            op[4 * g + 3]      = (float)u1[1];
            op[16 + 4 * g + 0] = (float)u2[0];
            op[16 + 4 * g + 1] = (float)u2[1];
            op[16 + 4 * g + 2] = (float)u3[0];
            op[16 + 4 * g + 3] = (float)u3[1];
        }
    } else {
        // ---------------- emb/bag path: 1 row per thread ----------------
        for (int i = tid; i < 1620; i += 256)
            tabs[i] = (i < 1552) ? ctab[i] : ktab[i - 1552];
        __syncthreads();
        const long row = (long)((int)blockIdx.x - nrnn) * 256 + tid;
        int id = ids_bt[row];
        int ch = id >> 4;                              // pad -> 96
        int co = (id >= GLYPH_DIM) ? 16 : (id & 15);   // pad -> 16
        f32x4 c0 = *(const f32x4*)&tabs[ch * 16 + 0];
        f32x4 c1 = *(const f32x4*)&tabs[ch * 16 + 4];
        f32x4 c2 = *(const f32x4*)&tabs[ch * 16 + 8];
        f32x4 c3 = *(const f32x4*)&tabs[ch * 16 + 12];
        f32x4 k0 = *(const f32x4*)&tabs[1552 + co * 4];
        float* gp = out_emb + row * 20;
        *(f32x4*)(gp + 0)  = c0;
        *(f32x4*)(gp + 4)  = c1;
        *(f32x4*)(gp + 8)  = c2;
        *(f32x4*)(gp + 12) = c3;
        *(f32x4*)(gp + 16) = k0;
        *(float2*)(out_bag + row * 2) = make_float2((float)ch, (float)co);
    }
}

extern "C" void kernel_launch(void* const* d_in, const int* in_sizes, int n_in,
                              void* d_out, int out_size, void* d_ws, size_t ws_size,
                              hipStream_t stream) {
    const int* gchar = (const int*)d_in[0];
    const int* gcol  = (const int*)d_in[1];
    const float* ctab = (const float*)d_in[2];
    const float* ktab = (const float*)d_in[3];
    const float* Wih  = (const float*)d_in[4];
    const float* Whh  = (const float*)d_in[5];
    const float* bih  = (const float*)d_in[6];
    const float* bhh  = (const float*)d_in[7];

    const int B = in_sizes[0] / HW;          // 4096
    float* out_h   = (float*)d_out;                    // B*32
    float* out_emb = out_h + (long)B * 32;             // B*64*20
    float* out_bag = out_emb + (long)B * 64 * 20;      // B*64*2

    unsigned short* ids_bt   = (unsigned short*)d_ws;                 // B*64 u16
    unsigned short* ids_tb16 = ids_bt + (long)B * 64;                 // B*64 u16
    int*            lens_g   = (int*)((char*)d_ws + (long)B * 64 * 4);// B ints

    k1_histo<<<B / 4, 256, 0, stream>>>(gchar, gcol, ids_bt, ids_tb16, lens_g);

    const int nrnn = B / 16;                 // 256 RNN blocks (first in grid)
    const int nemb = B / 4;                  // 1024 emb blocks
    k23_main<<<nrnn + nemb, 256, 0, stream>>>(
        ctab, ktab, Wih, Whh, bih, bhh, ids_bt, ids_tb16, lens_g,
        out_h, out_emb, out_bag, nrnn);
}

// Round 10
// 50.715 us; speedup vs baseline: 1.0726x; 1.0726x over previous
//
#include <hip/hip_runtime.h>
#include <hip/hip_bf16.h>

#define HW        1659      // 21*79
#define GLYPH_DIM 1536

typedef _Float16 half8  __attribute__((ext_vector_type(8)));
typedef _Float16 half2v __attribute__((ext_vector_type(2)));
typedef float    f32x4  __attribute__((ext_vector_type(4)));

__device__ __forceinline__ unsigned int pk(float a, float b) {
    return __builtin_bit_cast(unsigned int, __builtin_amdgcn_cvt_pkrtz(a, b));
}

__device__ __forceinline__ half8 h8u(unsigned int a, unsigned int b,
                                     unsigned int c, unsigned int d) {
    uint4 u = make_uint4(a, b, c, d);
    return __builtin_bit_cast(half8, u);
}

// f32 Pade(5,4) tanh: x(945+105y+y^2)/(945+420y+15y^2), y=x^2, clamp in +-4,
// out +-1. One v_rcp_f32, no div sequence. Max abs err < 1e-3 on R.
__device__ __forceinline__ float tanh_pade(float x) {
    float xc = fmaxf(fminf(x, 4.0f), -4.0f);
    float y  = xc * xc;
    float num = xc * fmaf(y, y + 105.0f, 945.0f);
    float den = fmaf(y, fmaf(y, 15.0f, 420.0f), 945.0f);
    float r = num * __builtin_amdgcn_rcpf(den);
    return fmaxf(fminf(r, 1.0f), -1.0f);
}

// ---------------- K1: histogram -> sorted unique ids + lens ----------------
__global__ __launch_bounds__(256, 8) void k1_histo(
    const int* __restrict__ gchar, const int* __restrict__ gcol,
    unsigned short* __restrict__ ids_bt,    // [B][64]
    unsigned short* __restrict__ ids_tb16,  // [B/16][64 t][16 b-in-group]
    int* __restrict__ lens_g)
{
    __shared__ unsigned int   mask[4][48];
    __shared__ unsigned short ids_s[4][64];

    const int tid = threadIdx.x;
    const int b0  = blockIdx.x * 4;

    if (tid < 192) ((unsigned int*)mask)[tid] = 0u;
    __syncthreads();

    const int4* cp = (const int4*)(gchar + (long)b0 * HW);
    const int4* kp = (const int4*)(gcol  + (long)b0 * HW);
    const int n4 = HW;
    int idx = tid;
    bool valid = idx < n4;
    int4 c = {}, k = {};
    if (valid) { c = cp[idx]; k = kp[idx]; }
    while (valid) {
        int  idx1 = idx + 256;
        bool v1   = idx1 < n4;
        int4 c1 = {}, k1 = {};
        if (v1) { c1 = cp[idx1]; k1 = kp[idx1]; }
        {
            int gg  = idx * 4;
            int bl0 = gg / HW;
            int rem = gg - bl0 * HW;
            int bl1 = bl0 + ((rem + 1) >= HW);
            int bl2 = bl0 + ((rem + 2) >= HW);
            int bl3 = bl0 + ((rem + 3) >= HW);
            int id0 = c.x * 16 + k.x;
            int id1 = c.y * 16 + k.y;
            int id2 = c.z * 16 + k.z;
            int id3 = c.w * 16 + k.w;
            // adjacent-duplicate skip: identical neighbor => redundant atomic
            atomicOr(&mask[bl0][id0 >> 5], 1u << (id0 & 31));
            if (id1 != id0 || bl1 != bl0) atomicOr(&mask[bl1][id1 >> 5], 1u << (id1 & 31));
            if (id2 != id1 || bl2 != bl1) atomicOr(&mask[bl2][id2 >> 5], 1u << (id2 & 31));
            if (id3 != id2 || bl3 != bl2) atomicOr(&mask[bl3][id3 >> 5], 1u << (id3 & 31));
        }
        idx = idx1; valid = v1; c = c1; k = k1;
    }
    __syncthreads();

    if (tid < 128) {
        const int bl  = tid >> 5;
        const int l32 = tid & 31;
        unsigned long long m = 0ull;
        if (l32 < 24)
            m = ((unsigned long long)mask[bl][2 * l32 + 1] << 32) |
                (unsigned long long)mask[bl][2 * l32];
        int cnt  = __popcll(m);
        int incl = cnt;
        #pragma unroll
        for (int d = 1; d < 32; d <<= 1) {
            int nb = __shfl_up(incl, d, 32);
            if (l32 >= d) incl += nb;
        }
        int excl  = incl - cnt;
        int total = __shfl(incl, 31, 32);
        if (l32 == 0) lens_g[b0 + bl] = min(total, 64);
        ids_s[bl][l32]      = GLYPH_DIM;
        ids_s[bl][l32 + 32] = GLYPH_DIM;
        unsigned long long mm = m;
        int r = excl;
        while (mm != 0ull && r < 64) {
            int bit = __builtin_ctzll(mm);
            ids_s[bl][r] = (unsigned short)(l32 * 64 + bit);
            ++r;
            mm &= (mm - 1ull);
        }
    }
    __syncthreads();

    if (tid < 128)
        ((unsigned int*)(ids_bt + (long)b0 * 64))[tid] = ((unsigned int*)ids_s)[tid];
    {
        const int bl = tid >> 6, t = tid & 63;
        const int b  = b0 + bl;
        ids_tb16[((long)(b >> 4) * 64 + t) * 16 + (b & 15)] = ids_s[bl][t];
    }
}

// ---------------- K23: blocks [0,64): RNN (4 waves x 1 chain of 16 batches);
// blocks [64,...): emb/bag (2 rows/thread). Small LDS -> high co-residency.
// tau(g,j) = {4g..4g+3, 16+4g..19+4g} consistently on A and B; C/D layout
// (col=lane&15=batch, row=(lane>>4)*4+reg) feeds next step's B-fragment.
__global__ __launch_bounds__(256, 4) void k23_main(
    const float* __restrict__ ctab, const float* __restrict__ ktab,
    const float* __restrict__ Wih, const float* __restrict__ Whh,
    const float* __restrict__ bih, const float* __restrict__ bhh,
    const unsigned short* __restrict__ ids_bt,
    const unsigned short* __restrict__ ids_tb16,
    const int* __restrict__ lens_g,
    float* __restrict__ out_h, float* __restrict__ out_emb,
    float* __restrict__ out_bag, int nrnn)
{
    __shared__ _Float16       tabsh[1664];       // f16 tables (RNN path)
    __shared__ unsigned short ids4[4][64][16];   // 8 KB ids   (RNN path)
    __shared__ float          tabs[1620];        // f32 tables (emb path)

    const int tid = threadIdx.x;

    if ((int)blockIdx.x < nrnn) {
        // ---------------- RNN path ----------------
        const int w = tid >> 6, l = tid & 63;
        const int n = l & 15,  g = l >> 4;
        const int bg = blockIdx.x * 4 + w;

        // stage f16 tables + this block's ids
        for (int i = tid; i < 1620; i += 256)
            tabsh[i] = (_Float16)((i < 1552) ? ctab[i] : ktab[i - 1552]);
        {
            const unsigned int* src =
                (const unsigned int*)(ids_tb16 + (long)blockIdx.x * 4096);
            unsigned int* dst = (unsigned int*)ids4;
            #pragma unroll
            for (int j = 0; j < 8; ++j) dst[tid + j * 256] = src[tid + j * 256];
        }

        half8 wihA0, wihA1, whhA0, whhA1;
        #pragma unroll
        for (int j = 0; j < 8; ++j) {
            int kk = (j < 4) ? (4 * g + j) : (12 + 4 * g + j);   // tau(g,j)
            wihA0[j] = (_Float16)((kk < 20) ? Wih[n * 20 + kk] : 0.0f);
            wihA1[j] = (_Float16)((kk < 20) ? Wih[(n + 16) * 20 + kk] : 0.0f);
            whhA0[j] = (_Float16)Whh[n * 32 + kk];
            whhA1[j] = (_Float16)Whh[(n + 16) * 32 + kk];
        }
        f32x4 bias0, bias1;
        #pragma unroll
        for (int i = 0; i < 4; ++i) {
            bias0[i] = bih[4 * g + i] + bhh[4 * g + i];
            bias1[i] = bih[16 + 4 * g + i] + bhh[16 + 4 * g + i];
        }
        const int len = lens_g[bg * 16 + n];
        __syncthreads();

        // x-fragment from LDS f16 tables (2 x ds_read_b64, off-chain)
        auto build = [&](int t) -> half8 {
            int id = ids4[w][t][n];
            int ch = id >> 4;
            int co = (id >= GLYPH_DIM) ? 16 : (id & 15);
            uint2 c8 = *(const uint2*)&tabsh[ch * 16 + 4 * g];
            uint2 k8 = make_uint2(0u, 0u);
            if (g == 0) k8 = *(const uint2*)&tabsh[1552 + co * 4];
            return h8u(c8.x, c8.y, k8.x, k8.y);
        };

        half8 x0  = build(0);
        f32x4 Pc0 = __builtin_amdgcn_mfma_f32_16x16x32_f16(wihA0, x0, bias0, 0, 0, 0);
        f32x4 Pc1 = __builtin_amdgcn_mfma_f32_16x16x32_f16(wihA1, x0, bias1, 0, 0, 0);
        unsigned int hw0 = 0u, hw1 = 0u, hw2 = 0u, hw3 = 0u;
        for (int t = 0; t < 64; ++t) {
            // prefetch next P (off the h-chain)
            half8 xn  = build((t < 63) ? t + 1 : 63);
            f32x4 Pn0 = __builtin_amdgcn_mfma_f32_16x16x32_f16(wihA0, xn, bias0, 0, 0, 0);
            f32x4 Pn1 = __builtin_amdgcn_mfma_f32_16x16x32_f16(wihA1, xn, bias1, 0, 0, 0);
            half8 hB = h8u(hw0, hw1, hw2, hw3);
            f32x4 a0 = __builtin_amdgcn_mfma_f32_16x16x32_f16(whhA0, hB, Pc0, 0, 0, 0);
            f32x4 a1 = __builtin_amdgcn_mfma_f32_16x16x32_f16(whhA1, hB, Pc1, 0, 0, 0);
            unsigned int t0 = pk(tanh_pade(a0[0]), tanh_pade(a0[1]));
            unsigned int t1 = pk(tanh_pade(a0[2]), tanh_pade(a0[3]));
            unsigned int t2 = pk(tanh_pade(a1[0]), tanh_pade(a1[1]));
            unsigned int t3 = pk(tanh_pade(a1[2]), tanh_pade(a1[3]));
            bool upd = (t < len);
            hw0 = upd ? t0 : hw0;
            hw1 = upd ? t1 : hw1;
            hw2 = upd ? t2 : hw2;
            hw3 = upd ? t3 : hw3;
            Pc0 = Pn0; Pc1 = Pn1;
        }
        float* op = out_h + (long)(bg * 16 + n) * 32;
        half2v u0 = __builtin_bit_cast(half2v, hw0);
        half2v u1 = __builtin_bit_cast(half2v, hw1);
        half2v u2 = __builtin_bit_cast(half2v, hw2);
        half2v u3 = __builtin_bit_cast(half2v, hw3);
        f32x4 o0 = {(float)u0[0], (float)u0[1], (float)u1[0], (float)u1[1]};
        f32x4 o1 = {(float)u2[0], (float)u2[1], (float)u3[0], (float)u3[1]};
        *(f32x4*)(op + 4 * g)      = o0;
        *(f32x4*)(op + 16 + 4 * g) = o1;
    } else {
        // ---------------- emb/bag path: 2 rows per thread ----------------
        for (int i = tid; i < 1620; i += 256)
            tabs[i] = (i < 1552) ? ctab[i] : ktab[i - 1552];
        __syncthreads();
        const long base = (long)((int)blockIdx.x - nrnn) * 512;
        #pragma unroll
        for (int rr = 0; rr < 2; ++rr) {
            const long row = base + rr * 256 + tid;
            int id = ids_bt[row];
            int ch = id >> 4;                              // pad -> 96
            int co = (id >= GLYPH_DIM) ? 16 : (id & 15);   // pad -> 16
            f32x4 c0 = *(const f32x4*)&tabs[ch * 16 + 0];
            f32x4 c1 = *(const f32x4*)&tabs[ch * 16 + 4];
            f32x4 c2 = *(const f32x4*)&tabs[ch * 16 + 8];
            f32x4 c3 = *(const f32x4*)&tabs[ch * 16 + 12];
            f32x4 k0 = *(const f32x4*)&tabs[1552 + co * 4];
            float* gp = out_emb + row * 20;
            *(f32x4*)(gp + 0)  = c0;
            *(f32x4*)(gp + 4)  = c1;
            *(f32x4*)(gp + 8)  = c2;
            *(f32x4*)(gp + 12) = c3;
            *(f32x4*)(gp + 16) = k0;
            *(float2*)(out_bag + row * 2) = make_float2((float)ch, (float)co);
        }
    }
}

extern "C" void kernel_launch(void* const* d_in, const int* in_sizes, int n_in,
                              void* d_out, int out_size, void* d_ws, size_t ws_size,
                              hipStream_t stream) {
    const int* gchar = (const int*)d_in[0];
    const int* gcol  = (const int*)d_in[1];
    const float* ctab = (const float*)d_in[2];
    const float* ktab = (const float*)d_in[3];
    const float* Wih  = (const float*)d_in[4];
    const float* Whh  = (const float*)d_in[5];
    const float* bih  = (const float*)d_in[6];
    const float* bhh  = (const float*)d_in[7];

    const int B = in_sizes[0] / HW;          // 4096
    float* out_h   = (float*)d_out;                    // B*32
    float* out_emb = out_h + (long)B * 32;             // B*64*20
    float* out_bag = out_emb + (long)B * 64 * 20;      // B*64*2

    unsigned short* ids_bt   = (unsigned short*)d_ws;                 // B*64 u16
    unsigned short* ids_tb16 = ids_bt + (long)B * 64;                 // B*64 u16
    int*            lens_g   = (int*)((char*)d_ws + (long)B * 64 * 4);// B ints

    k1_histo<<<B / 4, 256, 0, stream>>>(gchar, gcol, ids_bt, ids_tb16, lens_g);

    const int nrnn = B / 64;                 // 64 RNN blocks (first in grid)
    const int nemb = (B * 64) / 512;         // 512 emb blocks, 2 rows/thread
    k23_main<<<nrnn + nemb, 256, 0, stream>>>(
        ctab, ktab, Wih, Whh, bih, bhh, ids_bt, ids_tb16, lens_g,
        out_h, out_emb, out_bag, nrnn);
}

// Round 11
// 41.156 us; speedup vs baseline: 1.3217x; 1.2322x over previous
//
#include <hip/hip_runtime.h>
#include <hip/hip_bf16.h>

#define HW        1659      // 21*79
#define GLYPH_DIM 1536
#define NBL       8         // batches per block
#define THREADS   512       // 8 waves

typedef _Float16 half8  __attribute__((ext_vector_type(8)));
typedef _Float16 half2v __attribute__((ext_vector_type(2)));
typedef float    f32x4  __attribute__((ext_vector_type(4)));

__device__ __forceinline__ unsigned int pk(float a, float b) {
    return __builtin_bit_cast(unsigned int, __builtin_amdgcn_cvt_pkrtz(a, b));
}

__device__ __forceinline__ half8 h8u(unsigned int a, unsigned int b,
                                     unsigned int c, unsigned int d) {
    uint4 u = make_uint4(a, b, c, d);
    return __builtin_bit_cast(half8, u);
}

// f32 Pade(5,4) tanh: x(945+105y+y^2)/(945+420y+15y^2); clamp in +-4, out +-1.
__device__ __forceinline__ float tanh_pade(float x) {
    float xc = fmaxf(fminf(x, 4.0f), -4.0f);
    float y  = xc * xc;
    float num = xc * fmaf(y, y + 105.0f, 945.0f);
    float den = fmaf(y, fmaf(y, 15.0f, 420.0f), 945.0f);
    float r = num * __builtin_amdgcn_rcpf(den);
    return fmaxf(fminf(r, 1.0f), -1.0f);
}

// Fused: histogram (run-dedup'd LDS atomics) -> sorted unique -> coalesced
// emb/bag (waves 1-7) overlapped with MFMA RNN chain (wave 0).
// tau(g,j) = {4g..4g+3, 16+4g..19+4g} consistently on A and B fragments; C/D
// layout (col=lane&15=batch, row=(lane>>4)*4+reg) IS next step's B-fragment.
__global__ __launch_bounds__(THREADS, 2) void glyph_fused(
    const int* __restrict__ gchar, const int* __restrict__ gcol,
    const float* __restrict__ ctab, const float* __restrict__ ktab,
    const float* __restrict__ Wih, const float* __restrict__ Whh,
    const float* __restrict__ bih, const float* __restrict__ bhh,
    float* __restrict__ out_h, float* __restrict__ out_emb,
    float* __restrict__ out_bag)
{
    __shared__ unsigned int   mask[NBL][48];   // 1.5 KB
    __shared__ unsigned short ids_s[NBL][64];  // 1 KB
    __shared__ int            lens[NBL];
    __shared__ _Float16       tabsh[1664];     // f16 tables (RNN)   3.3 KB
    __shared__ float          tabs[1620];      // f32 tables (emb)   6.5 KB

    const int tid = threadIdx.x;
    const int b0  = blockIdx.x * NBL;
    const int n   = tid & 15, g = (tid >> 4) & 3;

    // ---- wave0: preload RNN weights (latency hides under phases A-B) ----
    half8 wihA0, wihA1, whhA0, whhA1;
    f32x4 bias0, bias1;
    if (tid < 64) {
        #pragma unroll
        for (int j = 0; j < 8; ++j) {
            int kk = (j < 4) ? (4 * g + j) : (12 + 4 * g + j);   // tau(g,j)
            wihA0[j] = (_Float16)((kk < 20) ? Wih[n * 20 + kk] : 0.0f);
            wihA1[j] = (_Float16)((kk < 20) ? Wih[(n + 16) * 20 + kk] : 0.0f);
            whhA0[j] = (_Float16)Whh[n * 32 + kk];
            whhA1[j] = (_Float16)Whh[(n + 16) * 32 + kk];
        }
        #pragma unroll
        for (int i = 0; i < 4; ++i) {
            bias0[i] = bih[4 * g + i] + bhh[4 * g + i];
            bias1[i] = bih[16 + 4 * g + i] + bhh[16 + 4 * g + i];
        }
    }

    // ---- zero bitmap + stage tables ----
    if (tid < NBL * 48) ((unsigned int*)mask)[tid] = 0u;
    for (int i = tid; i < 1664; i += THREADS) {
        float v = (i < 1552) ? ctab[i] : ((i < 1620) ? ktab[i - 1552] : 0.0f);
        tabsh[i] = (_Float16)v;
        if (i < 1620) tabs[i] = v;
    }
    __syncthreads();

    // ---- phase A: histogram with cross-lane run dedup.
    // Wave covers 256 contiguous glyphs per iteration; only run-heads emit
    // atomics (same-address LDS atomicOr serializes ~45-way on space runs).
    {
        const int4* cp = (const int4*)(gchar + (long)b0 * HW);
        const int4* kp = (const int4*)(gcol  + (long)b0 * HW);
        const int n4 = (NBL * HW) / 4;   // 3318
        const int lane = tid & 63;
        for (int idx = tid; idx < n4; idx += THREADS) {
            int4 c = cp[idx];
            int4 k = kp[idx];
            int gg  = idx * 4;
            int bl0 = gg / HW;               // const-div -> magic mul
            int rem = gg - bl0 * HW;
            int bl1 = bl0 + ((rem + 1) >= HW);
            int bl2 = bl0 + ((rem + 2) >= HW);
            int bl3 = bl0 + ((rem + 3) >= HW);
            int p0 = bl0 * 2048 + c.x * 16 + k.x;
            int p1 = bl1 * 2048 + c.y * 16 + k.y;
            int p2 = bl2 * 2048 + c.z * 16 + k.z;
            int p3 = bl3 * 2048 + c.w * 16 + k.w;
            int prev = __shfl_up(p3, 1);     // predecessor glyph (lane-1's last)
            if (lane == 0) prev = -1;
            if (p0 != prev) atomicOr(&mask[p0 >> 11][(p0 & 2047) >> 5], 1u << (p0 & 31));
            if (p1 != p0)   atomicOr(&mask[p1 >> 11][(p1 & 2047) >> 5], 1u << (p1 & 31));
            if (p2 != p1)   atomicOr(&mask[p2 >> 11][(p2 & 2047) >> 5], 1u << (p2 & 31));
            if (p3 != p2)   atomicOr(&mask[p3 >> 11][(p3 & 2047) >> 5], 1u << (p3 & 31));
        }
    }
    __syncthreads();

    // ---- phase B: first-64 sorted set bits per batch (tid<256) ----
    if (tid < NBL * 32) {
        const int bl  = tid >> 5;
        const int l32 = tid & 31;
        unsigned long long m = 0ull;
        if (l32 < 24)
            m = ((unsigned long long)mask[bl][2 * l32 + 1] << 32) |
                (unsigned long long)mask[bl][2 * l32];
        int cnt  = __popcll(m);
        int incl = cnt;
        #pragma unroll
        for (int d = 1; d < 32; d <<= 1) {
            int nb = __shfl_up(incl, d, 32);
            if (l32 >= d) incl += nb;
        }
        int excl  = incl - cnt;
        int total = __shfl(incl, 31, 32);
        if (l32 == 0) lens[bl] = min(total, 64);
        ids_s[bl][l32]      = GLYPH_DIM;   // sentinel prefill (same-wave order)
        ids_s[bl][l32 + 32] = GLYPH_DIM;
        unsigned long long mm = m;
        int r = excl;
        while (mm != 0ull && r < 64) {
            int bit = __builtin_ctzll(mm);
            ids_s[bl][r] = (unsigned short)(l32 * 64 + bit);
            ++r;
            mm &= (mm - 1ull);
        }
    }
    __syncthreads();

    if (tid >= 64) {
        // ---- waves 1-7: COALESCED emb + bag writes ----
        // emb float4 #i: row = i/5, part = i%5 (80 B row = 5 float4 exactly);
        // store address = base + i*16 -> consecutive lanes, consecutive 16B.
        float* eb = out_emb + (long)b0 * 1280;   // 8*64*20
        for (int i = tid - 64; i < NBL * 64 * 5; i += THREADS - 64) {
            int row  = i / 5;                    // const-div
            int part = i - row * 5;
            int id = ids_s[row >> 6][row & 63];
            int ch = id >> 4;
            int co = (id >= GLYPH_DIM) ? 16 : (id & 15);
            int off = (part < 4) ? (ch * 16 + part * 4) : (1552 + co * 4);
            *(f32x4*)(eb + i * 4) = *(const f32x4*)&tabs[off];
        }
        float* bb = out_bag + (long)b0 * 128;    // 8*64*2
        for (int i = tid - 64; i < NBL * 32; i += THREADS - 64) {  // 2 rows/f32x4
            int r0 = 2 * i, r1 = 2 * i + 1;
            int id0 = ids_s[r0 >> 6][r0 & 63];
            int id1 = ids_s[r1 >> 6][r1 & 63];
            f32x4 v;
            v[0] = (float)(id0 >> 4);
            v[1] = (float)((id0 >= GLYPH_DIM) ? 16 : (id0 & 15));
            v[2] = (float)(id1 >> 4);
            v[3] = (float)((id1 >= GLYPH_DIM) ? 16 : (id1 & 15));
            *(f32x4*)(bb + i * 4) = v;
        }
    } else {
        // ---- wave 0: serial MFMA RNN, 8 batches (cols 8-15 duplicate) ----
        const int nc  = n & (NBL - 1);
        const int len = lens[nc];

        int id0 = ids_s[nc][0];
        int idn = ids_s[nc][1];
        half8 x0;
        {
            int ch = id0 >> 4;
            int co = (id0 >= GLYPH_DIM) ? 16 : (id0 & 15);
            uint2 c8 = *(const uint2*)&tabsh[ch * 16 + 4 * g];
            uint2 k8 = make_uint2(0u, 0u);
            if (g == 0) k8 = *(const uint2*)&tabsh[1552 + co * 4];
            x0 = h8u(c8.x, c8.y, k8.x, k8.y);
        }
        f32x4 Pc0 = __builtin_amdgcn_mfma_f32_16x16x32_f16(wihA0, x0, bias0, 0, 0, 0);
        f32x4 Pc1 = __builtin_amdgcn_mfma_f32_16x16x32_f16(wihA1, x0, bias1, 0, 0, 0);
        unsigned int hw0 = 0u, hw1 = 0u, hw2 = 0u, hw3 = 0u;

        for (int t = 0; t < 64; ++t) {
            // issue loads for x_{t+1} early (consumed at end of body)
            int ch = idn >> 4;
            int co = (idn >= GLYPH_DIM) ? 16 : (idn & 15);
            uint2 c8 = *(const uint2*)&tabsh[ch * 16 + 4 * g];
            uint2 k8 = make_uint2(0u, 0u);
            if (g == 0) k8 = *(const uint2*)&tabsh[1552 + co * 4];
            int idn2 = ids_s[nc][(t < 62) ? t + 2 : 63];

            // serial chain: hB -> 2 MFMA -> tanh -> select
            half8 hB = h8u(hw0, hw1, hw2, hw3);
            f32x4 a0 = __builtin_amdgcn_mfma_f32_16x16x32_f16(whhA0, hB, Pc0, 0, 0, 0);
            f32x4 a1 = __builtin_amdgcn_mfma_f32_16x16x32_f16(whhA1, hB, Pc1, 0, 0, 0);
            unsigned int t0 = pk(tanh_pade(a0[0]), tanh_pade(a0[1]));
            unsigned int t1 = pk(tanh_pade(a0[2]), tanh_pade(a0[3]));
            unsigned int t2 = pk(tanh_pade(a1[0]), tanh_pade(a1[1]));
            unsigned int t3 = pk(tanh_pade(a1[2]), tanh_pade(a1[3]));
            bool upd = (t < len);
            hw0 = upd ? t0 : hw0;
            hw1 = upd ? t1 : hw1;
            hw2 = upd ? t2 : hw2;
            hw3 = upd ? t3 : hw3;

            // off-chain: next P from the just-landed x fragment
            half8 xn = h8u(c8.x, c8.y, k8.x, k8.y);
            Pc0 = __builtin_amdgcn_mfma_f32_16x16x32_f16(wihA0, xn, bias0, 0, 0, 0);
            Pc1 = __builtin_amdgcn_mfma_f32_16x16x32_f16(wihA1, xn, bias1, 0, 0, 0);
            idn = idn2;
        }

        if (n < NBL) {
            half2v u0 = __builtin_bit_cast(half2v, hw0);
            half2v u1 = __builtin_bit_cast(half2v, hw1);
            half2v u2 = __builtin_bit_cast(half2v, hw2);
            half2v u3 = __builtin_bit_cast(half2v, hw3);
            f32x4 o0 = {(float)u0[0], (float)u0[1], (float)u1[0], (float)u1[1]};
            f32x4 o1 = {(float)u2[0], (float)u2[1], (float)u3[0], (float)u3[1]};
            float* op = out_h + (long)(b0 + n) * 32;
            *(f32x4*)(op + 4 * g)      = o0;
            *(f32x4*)(op + 16 + 4 * g) = o1;
        }
    }
}

extern "C" void kernel_launch(void* const* d_in, const int* in_sizes, int n_in,
                              void* d_out, int out_size, void* d_ws, size_t ws_size,
                              hipStream_t stream) {
    const int* gchar = (const int*)d_in[0];
    const int* gcol  = (const int*)d_in[1];
    const float* ctab = (const float*)d_in[2];
    const float* ktab = (const float*)d_in[3];
    const float* Wih  = (const float*)d_in[4];
    const float* Whh  = (const float*)d_in[5];
    const float* bih  = (const float*)d_in[6];
    const float* bhh  = (const float*)d_in[7];

    const int B = in_sizes[0] / HW;          // 4096
    float* out_h   = (float*)d_out;                    // B*32
    float* out_emb = out_h + (long)B * 32;             // B*64*20
    float* out_bag = out_emb + (long)B * 64 * 20;      // B*64*2

    glyph_fused<<<B / NBL, THREADS, 0, stream>>>(
        gchar, gcol, ctab, ktab, Wih, Whh, bih, bhh, out_h, out_emb, out_bag);
}